// Round 2
// baseline (705.193 us; speedup 1.0000x reference)
//
#include <hip/hip_runtime.h>
#include <stdint.h>

#define B_TOT 8192
#define F 64
#define D 256
#define NPAIR 2016

typedef __bf16 bf16x8 __attribute__((ext_vector_type(8)));
typedef float f32x4 __attribute__((ext_vector_type(4)));

// One batch (64x256) per WAVE. No LDS, no barriers, no inter-wave coupling.
// Per-lane fragment set for mfma_f32_16x16x32_bf16 (verified mapping):
//   A/B frag for block blk, k-step kk: row = blk*16 + (lane&15),
//   cols = (lane>>4)*8 + kk*32 + (0..7)  -> 8 contiguous floats = 2x float4.
// Every element of the batch belongs to exactly one lane, so the whole batch
// lives in registers as bf16: frag[4][8] = 128 VGPRs.
__global__ __launch_bounds__(256, 2)   // cap 256 VGPR; ~8 waves/CU, no spill
void DotInteraction_kernel(const float* __restrict__ X, float* __restrict__ out)
{
    const int tid  = threadIdx.x;
    const int wave = tid >> 6;
    const int lane = tid & 63;
    const int r16  = lane & 15;
    const int quad = lane >> 4;

    const int b = blockIdx.x * 4 + wave;            // one batch per wave
    const float* __restrict__ xb = X + (size_t)b * (F * D);

    bf16x8 frag[4][8];   // [row-block][kk], all indices compile-time (unrolled)

#pragma unroll
    for (int blk = 0; blk < 4; ++blk) {
        const float* __restrict__ row = xb + (blk * 16 + r16) * D + quad * 8;
#pragma unroll
        for (int kk = 0; kk < 8; ++kk) {
            // two 16B loads, 128B apart; compiler folds into imm-offset dwordx4
            float4 f0 = *(const float4*)(row + kk * 32);
            float4 f1 = *(const float4*)(row + kk * 32 + 4);
            bf16x8 h = { (__bf16)f0.x, (__bf16)f0.y, (__bf16)f0.z, (__bf16)f0.w,
                         (__bf16)f1.x, (__bf16)f1.y, (__bf16)f1.z, (__bf16)f1.w };
            frag[blk][kk] = h;
        }
    }

    float* __restrict__ ob = out + (size_t)b * NPAIR;

    // 10 upper-triangular 16x16 tiles of the 64x64 Gram matrix, all from regs.
    // Diagonal tiles pass the same fragment for A and B (same rows/cols).
#pragma unroll
    for (int ti = 0; ti < 4; ++ti) {
#pragma unroll
        for (int tj = ti; tj < 4; ++tj) {
            f32x4 acc = {0.f, 0.f, 0.f, 0.f};
#pragma unroll
            for (int kk = 0; kk < 8; ++kk)
                acc = __builtin_amdgcn_mfma_f32_16x16x32_bf16(
                          frag[ti][kk], frag[tj][kk], acc, 0, 0, 0);

            // C/D layout: col = lane&15, row = quad*4 + reg  [verified mapping]
            const int j = tj * 16 + r16;
#pragma unroll
            for (int rr = 0; rr < 4; ++rr) {
                const int i = ti * 16 + quad * 4 + rr;
                if (j > i) {
                    const int p = (i * (127 - i)) / 2 + (j - i - 1);
                    ob[p] = acc[rr];
                }
            }
        }
    }
}

extern "C" void kernel_launch(void* const* d_in, const int* in_sizes, int n_in,
                              void* d_out, int out_size, void* d_ws, size_t ws_size,
                              hipStream_t stream) {
    const float* X = (const float*)d_in[0];
    float* out = (float*)d_out;
    DotInteraction_kernel<<<B_TOT / 4, 256, 0, stream>>>(X, out);
}